// Round 4
// baseline (1736.048 us; speedup 1.0000x reference)
//
#include <hip/hip_runtime.h>
#include <math.h>

// Problem constants (fixed by the reference setup)
#define B_SZ   64
#define C_SZ   12
#define T_SZ   2048
#define K_SZ   2048
#define LMAX   11
#define CMAX   11     // C-1
#define PL_PAD 1024
#define A_PARAM 7.0f

#define NW     8      // waves per block in main kernel
#define BLOCK_MAIN (NW * 64)

// ---------------------------------------------------------------------------
// Transpose: xT[c][t][b] = x[b][c][t]  (unpadded, 6.3 MB). lane = b -> writes
// perfectly coalesced; reads L1-reused 16x along t.
__global__ __launch_bounds__(256) void tr_kernel(const float* __restrict__ x,
                                                 float* __restrict__ xT) {
    const int c    = blockIdx.x;
    const int lane = threadIdx.x & 63;
    const int wid  = threadIdx.x >> 6;
    const int t0   = blockIdx.y * 128 + wid * 32;
    const float* xrow = x + ((size_t)lane * C_SZ + c) * T_SZ + t0;
    float* dst = xT + ((size_t)c * T_SZ + t0) * 64 + lane;
    #pragma unroll 8
    for (int i = 0; i < 32; ++i)
        dst[i * 64] = xrow[i];
}

// ---------------------------------------------------------------------------
template<int LC, int RR>
__device__ __forceinline__ void conv_all(
    const float* __restrict__ xT,
    const int*   __restrict__ sCh,
    const float  (* __restrict__ sW)[LMAX],
    int n, int d, int offr, int olen, float bias,
    int lane, int wid, float& psum, float& pmax)
{
    constexpr int NV = RR + LC - 1;
    const int d64    = d * 64;
    const int nj     = (olen + d - 1) / d;        // outputs per residue (max)
    const int njb    = (nj + RR - 1) / RR;
    const int nitems = d * njb;

    for (int it = wid; it < nitems; it += NW) {
        const int q  = it % d;
        const int jb = it / d;
        const int tq = q + jb * (RR * d);         // first output t of this item
        if (tq >= olen) continue;
        const int tpos0 = tq + offr;              // real x coord of tap 0

        float y[RR];
        #pragma unroll
        for (int r = 0; r < RR; ++r) y[r] = bias;

        const bool fast = (tpos0 >= 0) && (tpos0 + (NV - 1) * d < T_SZ);

        if (fast) {
            for (int c = 0; c < n; ++c) {
                const int rb = __builtin_amdgcn_readfirstlane(sCh[c] * T_SZ + tpos0);
                const float* p = xT + ((size_t)rb << 6) + lane;
                float v[NV];
                #pragma unroll
                for (int i = 0; i < NV; ++i) v[i] = p[(size_t)(i * d64)];
                #pragma unroll
                for (int l = 0; l < LC; ++l) {
                    const float wl = sW[c][l];
                    #pragma unroll
                    for (int r = 0; r < RR; ++r)
                        y[r] = fmaf(wl, v[l + r], y[r]);
                }
            }
        } else {
            for (int c = 0; c < n; ++c) {
                const int rb = __builtin_amdgcn_readfirstlane(sCh[c] * T_SZ);
                const float* p = xT + ((size_t)rb << 6) + lane;
                float v[NV];
                #pragma unroll
                for (int i = 0; i < NV; ++i) {
                    const int tp  = tpos0 + i * d;        // wave-uniform
                    const int tpc = min(max(tp, 0), T_SZ - 1);
                    const float f = p[(size_t)(tpc * 64)];
                    v[i] = ((unsigned)tp < (unsigned)T_SZ) ? f : 0.0f;
                }
                #pragma unroll
                for (int l = 0; l < LC; ++l) {
                    const float wl = sW[c][l];
                    #pragma unroll
                    for (int r = 0; r < RR; ++r)
                        y[r] = fmaf(wl, v[l + r], y[r]);
                }
            }
        }

        #pragma unroll
        for (int r = 0; r < RR; ++r) {
            const int t = tq + r * d;
            if (t < olen) {                       // wave-uniform branch
                psum += 1.0f / (1.0f + __expf(3.0f - A_PARAM * y[r]));
                pmax  = fmaxf(pmax, y[r]);
            }
        }
    }
}

__global__ __launch_bounds__(BLOCK_MAIN, 6) void rocket_tr(
    const float* __restrict__ xT,       // (C, T, 64)
    const float* __restrict__ weights,  // (K, CMAX, LMAX)
    const float* __restrict__ biases,
    const int*   __restrict__ ch_idx,   // (K, CMAX)
    const int*   __restrict__ dils,
    const int*   __restrict__ offs,
    const int*   __restrict__ olens,
    float*       __restrict__ out)      // (B, 2K)
{
    __shared__ float sW[CMAX][LMAX];
    __shared__ int   sCh[CMAX];
    __shared__ int   sMeta[2];
    __shared__ float sP[NW][64];
    __shared__ float sM[NW][64];

    const int k   = blockIdx.x;
    const int tid = threadIdx.x;

    if (tid < CMAX * LMAX)
        sW[tid / LMAX][tid % LMAX] = weights[(size_t)k * (CMAX * LMAX) + tid];
    if (tid < CMAX)
        sCh[tid] = ch_idx[(size_t)k * CMAX + tid];
    __syncthreads();

    if (tid == 0) {
        // Effective channel/tap counts (zero-padded rows/taps contribute 0).
        int n = 0, L = 0;
        for (int c = 0; c < CMAX; ++c) {
            bool nz = false;
            for (int l = 0; l < LMAX; ++l) {
                if (sW[c][l] != 0.0f) { nz = true; if (l + 1 > L) L = l + 1; }
            }
            if (nz) n = c + 1;
        }
        sMeta[0] = n; sMeta[1] = L;
    }
    __syncthreads();

    const int   n    = sMeta[0];
    const int   L    = sMeta[1];
    const int   d    = dils[k];
    const int   offr = offs[k] - PL_PAD;   // real x coord offset (may be <0)
    const int   olen = olens[k];
    const float bias = biases[k];
    const int   lane = tid & 63;
    const int   wid  = __builtin_amdgcn_readfirstlane(tid >> 6);

    float psum = 0.0f;
    float pmax = -INFINITY;

    if (d <= 64) {
        if (L <= 7)
            conv_all<7, 16>(xT, sCh, sW, n, d, offr, olen, bias, lane, wid, psum, pmax);
        else if (L <= 9)
            conv_all<9, 16>(xT, sCh, sW, n, d, offr, olen, bias, lane, wid, psum, pmax);
        else
            conv_all<11,16>(xT, sCh, sW, n, d, offr, olen, bias, lane, wid, psum, pmax);
    } else {
        if (L <= 7)
            conv_all<7,  8>(xT, sCh, sW, n, d, offr, olen, bias, lane, wid, psum, pmax);
        else if (L <= 9)
            conv_all<9,  8>(xT, sCh, sW, n, d, offr, olen, bias, lane, wid, psum, pmax);
        else
            conv_all<11, 8>(xT, sCh, sW, n, d, offr, olen, bias, lane, wid, psum, pmax);
    }

    sP[wid][lane] = psum;
    sM[wid][lane] = pmax;
    __syncthreads();

    if (tid < 64) {
        float s = 0.0f, m = -INFINITY;
        #pragma unroll
        for (int w = 0; w < NW; ++w) {
            s += sP[w][tid];
            m  = fmaxf(m, sM[w][tid]);
        }
        const float inv_olen = 1.0f / (float)olen;
        out[(size_t)tid * (2 * K_SZ) + 2 * k]     = s * inv_olen;
        out[(size_t)tid * (2 * K_SZ) + 2 * k + 1] = m;
    }
}

// ---------------------------------------------------------------------------
// Fallback (ws too small): simple checked-gather kernel, known correct.
__global__ __launch_bounds__(256) void rocket_fallback(
    const float* __restrict__ x,
    const float* __restrict__ weights,
    const float* __restrict__ biases,
    const int*   __restrict__ ch_idx,
    const int*   __restrict__ dils,
    const int*   __restrict__ offs,
    const int*   __restrict__ olens,
    float*       __restrict__ out)
{
    __shared__ float sW[CMAX][LMAX];
    __shared__ int   sCh[CMAX];
    __shared__ float sRed[2][4];

    const int k   = blockIdx.x;
    const int tid = threadIdx.x;

    if (tid < CMAX * LMAX)
        sW[tid / LMAX][tid % LMAX] = weights[(size_t)k * (CMAX * LMAX) + tid];
    if (tid < CMAX)
        sCh[tid] = ch_idx[(size_t)k * CMAX + tid];
    __syncthreads();

    const int   d    = dils[k];
    const int   off  = offs[k] - PL_PAD;
    const int   olen = olens[k];
    const float bias = biases[k];
    const int   lane = tid & 63;
    const int   wid  = tid >> 6;

    for (int b = blockIdx.y; b < B_SZ; b += gridDim.y) {
        float psum = 0.0f, pmax = -INFINITY;
        for (int t = tid; t < T_SZ; t += 256) {
            float y = bias;
            for (int c = 0; c < CMAX; ++c) {
                const float* xb = x + ((size_t)b * C_SZ + sCh[c]) * T_SZ;
                int pos = off + t;
                for (int l = 0; l < LMAX; ++l) {
                    const float xv = ((unsigned)pos < (unsigned)T_SZ) ? xb[pos] : 0.0f;
                    y = fmaf(sW[c][l], xv, y);
                    pos += d;
                }
            }
            if (t < olen) {
                psum += 1.0f / (1.0f + __expf(3.0f - A_PARAM * y));
                pmax = fmaxf(pmax, y);
            }
        }
        for (int o = 32; o > 0; o >>= 1) {
            psum += __shfl_down(psum, o, 64);
            pmax  = fmaxf(pmax, __shfl_down(pmax, o, 64));
        }
        if (lane == 0) { sRed[0][wid] = psum; sRed[1][wid] = pmax; }
        __syncthreads();
        if (tid == 0) {
            const float s = sRed[0][0] + sRed[0][1] + sRed[0][2] + sRed[0][3];
            const float m = fmaxf(fmaxf(sRed[1][0], sRed[1][1]),
                                  fmaxf(sRed[1][2], sRed[1][3]));
            out[(size_t)b * (2 * K_SZ) + 2 * k]     = s / (float)olen;
            out[(size_t)b * (2 * K_SZ) + 2 * k + 1] = m;
        }
        __syncthreads();
    }
}

// ---------------------------------------------------------------------------
extern "C" void kernel_launch(void* const* d_in, const int* in_sizes, int n_in,
                              void* d_out, int out_size, void* d_ws, size_t ws_size,
                              hipStream_t stream) {
    const float* x       = (const float*)d_in[0];
    const float* weights = (const float*)d_in[1];
    const float* biases  = (const float*)d_in[2];
    const int*   ch_idx  = (const int*)  d_in[3];
    const int*   dils    = (const int*)  d_in[4];
    const int*   offs    = (const int*)  d_in[5];
    const int*   olens   = (const int*)  d_in[6];
    float*       out     = (float*)d_out;

    const size_t need = (size_t)C_SZ * T_SZ * 64 * sizeof(float);   // 6.3 MB

    if (ws_size >= need) {
        float* xT = (float*)d_ws;
        dim3 tgrid(C_SZ, T_SZ / 128);
        tr_kernel<<<tgrid, 256, 0, stream>>>(x, xT);
        rocket_tr<<<K_SZ, BLOCK_MAIN, 0, stream>>>(xT, weights, biases, ch_idx,
                                                   dils, offs, olens, out);
    } else {
        dim3 grid(K_SZ, 16);
        rocket_fallback<<<grid, 256, 0, stream>>>(x, weights, biases, ch_idx,
                                                  dils, offs, olens, out);
    }
}

// Round 5
// 1184.026 us; speedup vs baseline: 1.4662x; 1.4662x over previous
//
#include <hip/hip_runtime.h>
#include <hip/hip_bf16.h>
#include <math.h>

// Problem constants (fixed by the reference setup)
#define B_SZ   64
#define C_SZ   12
#define T_SZ   2048
#define K_SZ   2048
#define LMAX   11
#define CMAX   11     // C-1
#define PL_PAD 1024
#define A_PARAM 7.0f

#define NW     8      // waves per block in main kernel
#define BLOCK_MAIN (NW * 64)
#define R      8      // outputs per thread item (dilation-strided register tile)

// ---------------------------------------------------------------------------
// Transpose to bf16: xT[c][t][b] = bf16(x[b][c][t]). 3.15 MB -> fits per-XCD L2.
__global__ __launch_bounds__(256) void trb_kernel(const float* __restrict__ x,
                                                  __hip_bfloat16* __restrict__ xT) {
    const int c    = blockIdx.x;
    const int lane = threadIdx.x & 63;
    const int wid  = threadIdx.x >> 6;
    const int t0   = blockIdx.y * 128 + wid * 32;
    const float* xrow = x + ((size_t)lane * C_SZ + c) * T_SZ + t0;
    __hip_bfloat16* dst = xT + ((size_t)c * T_SZ + t0) * 64 + lane;
    #pragma unroll 8
    for (int i = 0; i < 32; ++i)
        dst[i * 64] = __float2bfloat16(xrow[i]);
}

// ---------------------------------------------------------------------------
template<int LC>
__device__ __forceinline__ void conv_all(
    const __hip_bfloat16* __restrict__ xT,
    const int*   __restrict__ sCh,
    const float  (* __restrict__ sW)[LMAX],
    int n, int d, int offr, int olen, float bias,
    int lane, int wid, float& psum, float& pmax)
{
    constexpr int NV = R + LC - 1;
    const int nj     = (T_SZ + d - 1) / d;   // uniform work: iterate t over [0,T)
    const int njb    = (nj + R - 1) / R;
    const int nitems = d * njb;

    for (int it = wid; it < nitems; it += NW) {
        const int q  = it % d;
        const int jb = it / d;
        const int tq = q + jb * (R * d);          // first output t of this item
        if (tq >= T_SZ) continue;
        const int tpos0 = tq + offr;              // real x coord of tap 0

        float y[R];
        #pragma unroll
        for (int r = 0; r < R; ++r) y[r] = bias;

        const bool fast = (tpos0 >= 0) && (tpos0 + (NV - 1) * d < T_SZ);

        if (fast) {
            for (int c = 0; c < n; ++c) {
                const int rb = __builtin_amdgcn_readfirstlane(sCh[c] * T_SZ + tpos0);
                const __hip_bfloat16* p = xT + ((size_t)rb << 6) + lane;
                float v[NV];
                #pragma unroll
                for (int i = 0; i < NV; ++i)
                    v[i] = __bfloat162float(p[(size_t)(i * d) << 6]);
                #pragma unroll
                for (int l = 0; l < LC; ++l) {
                    const float wl = sW[c][l];
                    #pragma unroll
                    for (int r = 0; r < R; ++r)
                        y[r] = fmaf(wl, v[l + r], y[r]);
                }
            }
        } else {
            for (int c = 0; c < n; ++c) {
                const int rb = __builtin_amdgcn_readfirstlane(sCh[c] * T_SZ);
                const __hip_bfloat16* p = xT + ((size_t)rb << 6) + lane;
                float v[NV];
                #pragma unroll
                for (int i = 0; i < NV; ++i) {
                    const int tp  = tpos0 + i * d;              // wave-uniform
                    const int tpc = min(max(tp, 0), T_SZ - 1);
                    const float f = __bfloat162float(p[(size_t)tpc << 6]);
                    v[i] = ((unsigned)tp < (unsigned)T_SZ) ? f : 0.0f;
                }
                #pragma unroll
                for (int l = 0; l < LC; ++l) {
                    const float wl = sW[c][l];
                    #pragma unroll
                    for (int r = 0; r < R; ++r)
                        y[r] = fmaf(wl, v[l + r], y[r]);
                }
            }
        }

        #pragma unroll
        for (int r = 0; r < R; ++r) {
            const int t = tq + r * d;
            if (t < olen) {                       // wave-uniform branch
                psum += 1.0f / (1.0f + __expf(3.0f - A_PARAM * y[r]));
                pmax  = fmaxf(pmax, y[r]);
            }
        }
    }
}

__global__ __launch_bounds__(BLOCK_MAIN, 8) void rocket_tr(
    const __hip_bfloat16* __restrict__ xT,   // (C, T, 64) bf16
    const float* __restrict__ weights,       // (K, CMAX, LMAX)
    const float* __restrict__ biases,
    const int*   __restrict__ ch_idx,        // (K, CMAX)
    const int*   __restrict__ dils,
    const int*   __restrict__ offs,
    const int*   __restrict__ olens,
    float*       __restrict__ out)           // (B, 2K)
{
    __shared__ float sW[CMAX][LMAX];
    __shared__ int   sCh[CMAX];
    __shared__ int   sMeta[2];
    __shared__ float sP[NW][64];
    __shared__ float sM[NW][64];

    const int k   = blockIdx.x;
    const int tid = threadIdx.x;

    if (tid < CMAX * LMAX)
        sW[tid / LMAX][tid % LMAX] = weights[(size_t)k * (CMAX * LMAX) + tid];
    if (tid < CMAX)
        sCh[tid] = ch_idx[(size_t)k * CMAX + tid];
    __syncthreads();

    if (tid == 0) {
        // Effective channel/tap counts (zero-padded rows/taps contribute 0).
        int n = 0, L = 0;
        for (int c = 0; c < CMAX; ++c) {
            bool nz = false;
            for (int l = 0; l < LMAX; ++l) {
                if (sW[c][l] != 0.0f) { nz = true; if (l + 1 > L) L = l + 1; }
            }
            if (nz) n = c + 1;
        }
        sMeta[0] = n; sMeta[1] = L;
    }
    __syncthreads();

    const int   n    = sMeta[0];
    const int   L    = sMeta[1];
    const int   d    = dils[k];
    const int   offr = offs[k] - PL_PAD;   // real x coord offset (may be <0)
    const int   olen = olens[k];
    const float bias = biases[k];
    const int   lane = tid & 63;
    const int   wid  = __builtin_amdgcn_readfirstlane(tid >> 6);

    float psum = 0.0f;
    float pmax = -INFINITY;

    if (L <= 7)
        conv_all<7 >(xT, sCh, sW, n, d, offr, olen, bias, lane, wid, psum, pmax);
    else if (L <= 9)
        conv_all<9 >(xT, sCh, sW, n, d, offr, olen, bias, lane, wid, psum, pmax);
    else
        conv_all<11>(xT, sCh, sW, n, d, offr, olen, bias, lane, wid, psum, pmax);

    sP[wid][lane] = psum;
    sM[wid][lane] = pmax;
    __syncthreads();

    if (tid < 64) {
        float s = 0.0f, m = -INFINITY;
        #pragma unroll
        for (int w = 0; w < NW; ++w) {
            s += sP[w][tid];
            m  = fmaxf(m, sM[w][tid]);
        }
        const float inv_olen = 1.0f / (float)olen;
        out[(size_t)tid * (2 * K_SZ) + 2 * k]     = s * inv_olen;
        out[(size_t)tid * (2 * K_SZ) + 2 * k + 1] = m;
    }
}

// ---------------------------------------------------------------------------
// Fallback (ws too small): simple checked-gather kernel, known correct.
__global__ __launch_bounds__(256) void rocket_fallback(
    const float* __restrict__ x,
    const float* __restrict__ weights,
    const float* __restrict__ biases,
    const int*   __restrict__ ch_idx,
    const int*   __restrict__ dils,
    const int*   __restrict__ offs,
    const int*   __restrict__ olens,
    float*       __restrict__ out)
{
    __shared__ float sW[CMAX][LMAX];
    __shared__ int   sCh[CMAX];
    __shared__ float sRed[2][4];

    const int k   = blockIdx.x;
    const int tid = threadIdx.x;

    if (tid < CMAX * LMAX)
        sW[tid / LMAX][tid % LMAX] = weights[(size_t)k * (CMAX * LMAX) + tid];
    if (tid < CMAX)
        sCh[tid] = ch_idx[(size_t)k * CMAX + tid];
    __syncthreads();

    const int   d    = dils[k];
    const int   off  = offs[k] - PL_PAD;
    const int   olen = olens[k];
    const float bias = biases[k];
    const int   lane = tid & 63;
    const int   wid  = tid >> 6;

    for (int b = blockIdx.y; b < B_SZ; b += gridDim.y) {
        float psum = 0.0f, pmax = -INFINITY;
        for (int t = tid; t < T_SZ; t += 256) {
            float y = bias;
            for (int c = 0; c < CMAX; ++c) {
                const float* xb = x + ((size_t)b * C_SZ + sCh[c]) * T_SZ;
                int pos = off + t;
                for (int l = 0; l < LMAX; ++l) {
                    const float xv = ((unsigned)pos < (unsigned)T_SZ) ? xb[pos] : 0.0f;
                    y = fmaf(sW[c][l], xv, y);
                    pos += d;
                }
            }
            if (t < olen) {
                psum += 1.0f / (1.0f + __expf(3.0f - A_PARAM * y));
                pmax = fmaxf(pmax, y);
            }
        }
        for (int o = 32; o > 0; o >>= 1) {
            psum += __shfl_down(psum, o, 64);
            pmax  = fmaxf(pmax, __shfl_down(pmax, o, 64));
        }
        if (lane == 0) { sRed[0][wid] = psum; sRed[1][wid] = pmax; }
        __syncthreads();
        if (tid == 0) {
            const float s = sRed[0][0] + sRed[0][1] + sRed[0][2] + sRed[0][3];
            const float m = fmaxf(fmaxf(sRed[1][0], sRed[1][1]),
                                  fmaxf(sRed[1][2], sRed[1][3]));
            out[(size_t)b * (2 * K_SZ) + 2 * k]     = s / (float)olen;
            out[(size_t)b * (2 * K_SZ) + 2 * k + 1] = m;
        }
        __syncthreads();
    }
}

// ---------------------------------------------------------------------------
extern "C" void kernel_launch(void* const* d_in, const int* in_sizes, int n_in,
                              void* d_out, int out_size, void* d_ws, size_t ws_size,
                              hipStream_t stream) {
    const float* x       = (const float*)d_in[0];
    const float* weights = (const float*)d_in[1];
    const float* biases  = (const float*)d_in[2];
    const int*   ch_idx  = (const int*)  d_in[3];
    const int*   dils    = (const int*)  d_in[4];
    const int*   offs    = (const int*)  d_in[5];
    const int*   olens   = (const int*)  d_in[6];
    float*       out     = (float*)d_out;

    const size_t need = (size_t)C_SZ * T_SZ * 64 * sizeof(__hip_bfloat16); // 3.15 MB

    if (ws_size >= need) {
        __hip_bfloat16* xT = (__hip_bfloat16*)d_ws;
        dim3 tgrid(C_SZ, T_SZ / 128);
        trb_kernel<<<tgrid, 256, 0, stream>>>(x, xT);
        rocket_tr<<<K_SZ, BLOCK_MAIN, 0, stream>>>(xT, weights, biases, ch_idx,
                                                   dils, offs, olens, out);
    } else {
        dim3 grid(K_SZ, 16);
        rocket_fallback<<<grid, 256, 0, stream>>>(x, weights, biases, ch_idx,
                                                  dils, offs, olens, out);
    }
}

// Round 6
// 749.810 us; speedup vs baseline: 2.3153x; 1.5791x over previous
//
#include <hip/hip_runtime.h>
#include <hip/hip_bf16.h>
#include <math.h>

// Problem constants (fixed by the reference setup)
#define B_SZ   64
#define C_SZ   12
#define T_SZ   2048
#define K_SZ   2048
#define LMAX   11
#define CMAX   11     // C-1
#define PL_PAD 1024
#define A_PARAM 7.0f

#define NW     8      // waves per block in main kernel
#define BLOCK_MAIN (NW * 64)
#define R      8      // outputs per thread item (dilation-strided register tile)

// ---------------------------------------------------------------------------
// Transpose to bf16: xT[c][t][b] = bf16(x[b][c][t]). 3.15 MB -> fits per-XCD L2.
__global__ __launch_bounds__(256) void trb_kernel(const float* __restrict__ x,
                                                  __hip_bfloat16* __restrict__ xT) {
    const int c    = blockIdx.x;
    const int lane = threadIdx.x & 63;
    const int wid  = threadIdx.x >> 6;
    const int t0   = blockIdx.y * 128 + wid * 32;
    const float* xrow = x + ((size_t)lane * C_SZ + c) * T_SZ + t0;
    __hip_bfloat16* dst = xT + ((size_t)c * T_SZ + t0) * 64 + lane;
    #pragma unroll 8
    for (int i = 0; i < 32; ++i)
        dst[i * 64] = __float2bfloat16(xrow[i]);
}

// ---------------------------------------------------------------------------
// Schedule: cost[k] = n*L (from nonzero weight pattern), bitonic sort keys
// descending so heavy kernels dispatch first (LPT packing -> smaller tail).
__global__ __launch_bounds__(1024) void sched_kernel(const float* __restrict__ w,
                                                     unsigned* __restrict__ perm) {
    __shared__ unsigned key[K_SZ];
    const int tid = threadIdx.x;

    for (int k = tid; k < K_SZ; k += 1024) {
        const float* wk = w + (size_t)k * (CMAX * LMAX);
        int n = 0, L = 0;
        for (int e = 0; e < CMAX * LMAX; ++e) {
            if (wk[e] != 0.0f) {
                const int c = e / LMAX, l = e % LMAX;
                n = max(n, c + 1);
                L = max(L, l + 1);
            }
        }
        key[k] = ((unsigned)(n * L) << 11) | (unsigned)k;
    }
    __syncthreads();

    for (int ksz = 2; ksz <= K_SZ; ksz <<= 1) {
        for (int j = ksz >> 1; j > 0; j >>= 1) {
            for (int i = tid; i < K_SZ; i += 1024) {
                const int ixj = i ^ j;
                if (ixj > i) {
                    const unsigned a = key[i], b = key[ixj];
                    const bool sw = ((i & ksz) == 0) ? (a < b) : (a > b); // descending
                    if (sw) { key[i] = b; key[ixj] = a; }
                }
            }
            __syncthreads();
        }
    }
    for (int i = tid; i < K_SZ; i += 1024)
        perm[i] = key[i] & 0x7FFu;
}

// ---------------------------------------------------------------------------
template<int LC>
__device__ __forceinline__ void conv_all(
    const __hip_bfloat16* __restrict__ xT,
    const int*   __restrict__ sCh,
    const float  (* __restrict__ sW)[LMAX],
    int n, int d, int offr, int olen, float bias,
    int lane, int wid, float& psum, float& pmax)
{
    constexpr int NV = R + LC - 1;
    const int nj   = (T_SZ + d - 1) / d;          // outputs per residue chain
    const int njb  = (nj + R - 1) / R;            // items per chain
    const int S    = (d >= NW) ? 1 : ((NW + d - 1) / d);  // segments per chain
    const int len  = (njb + S - 1) / S;
    const int nunits = d * S;

    for (int u = wid; u < nunits; u += NW) {
        int q, seg;
        if (S == 1) { q = u; seg = 0; }            // avoids runtime div for d>=NW
        else        { q = u % d; seg = u / d; }
        const int jb0 = seg * len;
        const int jb1 = min(njb, jb0 + len);

        for (int jb = jb0; jb < jb1; ++jb) {
            const int tq = q + jb * (R * d);       // first output t of this item
            if (tq >= T_SZ) break;
            const int tpos0 = tq + offr;           // real x coord of tap 0

            float y[R];
            #pragma unroll
            for (int r = 0; r < R; ++r) y[r] = bias;

            const bool fast = (tpos0 >= 0) && (tpos0 + (NV - 1) * d < T_SZ);

            if (fast) {
                for (int c = 0; c < n; ++c) {
                    const int rb = __builtin_amdgcn_readfirstlane(sCh[c] * T_SZ + tpos0);
                    const __hip_bfloat16* rp = xT + ((size_t)rb << 6);  // uniform ptr
                    float v[NV];
                    #pragma unroll
                    for (int i = 0; i < NV; ++i) {
                        v[i] = __bfloat162float(rp[lane]);   // saddr + lane*2
                        rp += (d << 6);                      // uniform SALU bump
                    }
                    #pragma unroll
                    for (int l = 0; l < LC; ++l) {
                        const float wl = sW[c][l];
                        #pragma unroll
                        for (int r = 0; r < R; ++r)
                            y[r] = fmaf(wl, v[l + r], y[r]);
                    }
                }
            } else {
                for (int c = 0; c < n; ++c) {
                    const int rb = __builtin_amdgcn_readfirstlane(sCh[c] * T_SZ);
                    const __hip_bfloat16* row = xT + ((size_t)rb << 6);
                    float v[NV];
                    #pragma unroll
                    for (int i = 0; i < NV; ++i) {
                        const int tp  = tpos0 + i * d;              // wave-uniform
                        const int tpc = min(max(tp, 0), T_SZ - 1);  // scalar clamp
                        const float f = __bfloat162float(row[(tpc << 6) + lane]);
                        v[i] = ((unsigned)tp < (unsigned)T_SZ) ? f : 0.0f;
                    }
                    #pragma unroll
                    for (int l = 0; l < LC; ++l) {
                        const float wl = sW[c][l];
                        #pragma unroll
                        for (int r = 0; r < R; ++r)
                            y[r] = fmaf(wl, v[l + r], y[r]);
                    }
                }
            }

            #pragma unroll
            for (int r = 0; r < R; ++r) {
                const int t = tq + r * d;
                if (t < olen) {                    // wave-uniform branch
                    psum += 1.0f / (1.0f + __expf(3.0f - A_PARAM * y[r]));
                    pmax  = fmaxf(pmax, y[r]);
                }
            }
        }
    }
}

__global__ __launch_bounds__(BLOCK_MAIN, 8) void rocket_tr(
    const __hip_bfloat16* __restrict__ xT,   // (C, T, 64) bf16
    const unsigned* __restrict__ perm,       // heavy-first block -> k map
    const float* __restrict__ weights,       // (K, CMAX, LMAX)
    const float* __restrict__ biases,
    const int*   __restrict__ ch_idx,        // (K, CMAX)
    const int*   __restrict__ dils,
    const int*   __restrict__ offs,
    const int*   __restrict__ olens,
    float*       __restrict__ out)           // (B, 2K)
{
    __shared__ float sW[CMAX][LMAX];
    __shared__ int   sCh[CMAX];
    __shared__ int   sMeta[2];
    __shared__ float sP[NW][64];
    __shared__ float sM[NW][64];

    const int k   = (int)perm[blockIdx.x];
    const int tid = threadIdx.x;

    if (tid < CMAX * LMAX)
        sW[tid / LMAX][tid % LMAX] = weights[(size_t)k * (CMAX * LMAX) + tid];
    if (tid < CMAX)
        sCh[tid] = ch_idx[(size_t)k * CMAX + tid];
    __syncthreads();

    if (tid == 0) {
        // Effective channel/tap counts (zero-padded rows/taps contribute 0).
        int n = 0, L = 0;
        for (int c = 0; c < CMAX; ++c) {
            bool nz = false;
            for (int l = 0; l < LMAX; ++l) {
                if (sW[c][l] != 0.0f) { nz = true; if (l + 1 > L) L = l + 1; }
            }
            if (nz) n = c + 1;
        }
        sMeta[0] = n; sMeta[1] = L;
    }
    __syncthreads();

    const int   n    = sMeta[0];
    const int   L    = sMeta[1];
    const int   d    = dils[k];
    const int   offr = offs[k] - PL_PAD;   // real x coord offset (may be <0)
    const int   olen = olens[k];
    const float bias = biases[k];
    const int   lane = tid & 63;
    const int   wid  = __builtin_amdgcn_readfirstlane(tid >> 6);

    float psum = 0.0f;
    float pmax = -INFINITY;

    if (L <= 7)
        conv_all<7 >(xT, sCh, sW, n, d, offr, olen, bias, lane, wid, psum, pmax);
    else if (L <= 9)
        conv_all<9 >(xT, sCh, sW, n, d, offr, olen, bias, lane, wid, psum, pmax);
    else
        conv_all<11>(xT, sCh, sW, n, d, offr, olen, bias, lane, wid, psum, pmax);

    sP[wid][lane] = psum;
    sM[wid][lane] = pmax;
    __syncthreads();

    if (tid < 64) {
        float s = 0.0f, m = -INFINITY;
        #pragma unroll
        for (int w = 0; w < NW; ++w) {
            s += sP[w][tid];
            m  = fmaxf(m, sM[w][tid]);
        }
        const float inv_olen = 1.0f / (float)olen;
        out[(size_t)tid * (2 * K_SZ) + 2 * k]     = s * inv_olen;
        out[(size_t)tid * (2 * K_SZ) + 2 * k + 1] = m;
    }
}

// ---------------------------------------------------------------------------
// Fallback (ws too small): simple checked-gather kernel, known correct.
__global__ __launch_bounds__(256) void rocket_fallback(
    const float* __restrict__ x,
    const float* __restrict__ weights,
    const float* __restrict__ biases,
    const int*   __restrict__ ch_idx,
    const int*   __restrict__ dils,
    const int*   __restrict__ offs,
    const int*   __restrict__ olens,
    float*       __restrict__ out)
{
    __shared__ float sW[CMAX][LMAX];
    __shared__ int   sCh[CMAX];
    __shared__ float sRed[2][4];

    const int k   = blockIdx.x;
    const int tid = threadIdx.x;

    if (tid < CMAX * LMAX)
        sW[tid / LMAX][tid % LMAX] = weights[(size_t)k * (CMAX * LMAX) + tid];
    if (tid < CMAX)
        sCh[tid] = ch_idx[(size_t)k * CMAX + tid];
    __syncthreads();

    const int   d    = dils[k];
    const int   off  = offs[k] - PL_PAD;
    const int   olen = olens[k];
    const float bias = biases[k];
    const int   lane = tid & 63;
    const int   wid  = tid >> 6;

    for (int b = blockIdx.y; b < B_SZ; b += gridDim.y) {
        float psum = 0.0f, pmax = -INFINITY;
        for (int t = tid; t < T_SZ; t += 256) {
            float y = bias;
            for (int c = 0; c < CMAX; ++c) {
                const float* xb = x + ((size_t)b * C_SZ + sCh[c]) * T_SZ;
                int pos = off + t;
                for (int l = 0; l < LMAX; ++l) {
                    const float xv = ((unsigned)pos < (unsigned)T_SZ) ? xb[pos] : 0.0f;
                    y = fmaf(sW[c][l], xv, y);
                    pos += d;
                }
            }
            if (t < olen) {
                psum += 1.0f / (1.0f + __expf(3.0f - A_PARAM * y));
                pmax = fmaxf(pmax, y);
            }
        }
        for (int o = 32; o > 0; o >>= 1) {
            psum += __shfl_down(psum, o, 64);
            pmax  = fmaxf(pmax, __shfl_down(pmax, o, 64));
        }
        if (lane == 0) { sRed[0][wid] = psum; sRed[1][wid] = pmax; }
        __syncthreads();
        if (tid == 0) {
            const float s = sRed[0][0] + sRed[0][1] + sRed[0][2] + sRed[0][3];
            const float m = fmaxf(fmaxf(sRed[1][0], sRed[1][1]),
                                  fmaxf(sRed[1][2], sRed[1][3]));
            out[(size_t)b * (2 * K_SZ) + 2 * k]     = s / (float)olen;
            out[(size_t)b * (2 * K_SZ) + 2 * k + 1] = m;
        }
        __syncthreads();
    }
}

// ---------------------------------------------------------------------------
extern "C" void kernel_launch(void* const* d_in, const int* in_sizes, int n_in,
                              void* d_out, int out_size, void* d_ws, size_t ws_size,
                              hipStream_t stream) {
    const float* x       = (const float*)d_in[0];
    const float* weights = (const float*)d_in[1];
    const float* biases  = (const float*)d_in[2];
    const int*   ch_idx  = (const int*)  d_in[3];
    const int*   dils    = (const int*)  d_in[4];
    const int*   offs    = (const int*)  d_in[5];
    const int*   olens   = (const int*)  d_in[6];
    float*       out     = (float*)d_out;

    const size_t xt_bytes = (size_t)C_SZ * T_SZ * 64 * sizeof(__hip_bfloat16); // 3.15 MB
    const size_t need     = xt_bytes + K_SZ * sizeof(unsigned);

    if (ws_size >= need) {
        __hip_bfloat16* xT   = (__hip_bfloat16*)d_ws;
        unsigned*       perm = (unsigned*)((char*)d_ws + xt_bytes);
        dim3 tgrid(C_SZ, T_SZ / 128);
        trb_kernel<<<tgrid, 256, 0, stream>>>(x, xT);
        sched_kernel<<<1, 1024, 0, stream>>>(weights, perm);
        rocket_tr<<<K_SZ, BLOCK_MAIN, 0, stream>>>(xT, perm, weights, biases,
                                                   ch_idx, dils, offs, olens, out);
    } else {
        dim3 grid(K_SZ, 16);
        rocket_fallback<<<grid, 256, 0, stream>>>(x, weights, biases, ch_idx,
                                                  dils, offs, olens, out);
    }
}